// Round 19
// baseline (113.766 us; speedup 1.0000x reference)
//
#include <hip/hip_runtime.h>

// Cost volume, D=4: out[b,s,h,w] = mean_c feat1[b,c,h,w] * feat2[b,c,h,w+s-4]
// feat1/feat2: (8, 256, 96, 320) f32; out: (8, 9, 96, 320) f32.
// R18 = R17 structure (RPB=3, 256 blocks = all CUs, depth-3-pair register
// prefetch, 2 channels/STEP, padded-LDS feat2 windows, lgkmcnt(0)+raw-barrier
// pinning, exact-write float4 epilogue) + intra-block CHANNEL-GROUP split on
// the SLOW thread index: 480 threads = 2 cgs x 240; cg owns 128 channels;
// per-wave load geometry identical to R17. Cross-cg sum via tiny LDS stage.
// Why: R16/R17 showed per-CU delivered BW scales with waves (~5.7 GB/s/wave,
// latency-bound STEP schedule); chip is at 5.5 of ~6.3 TB/s. 7.5 waves/CU
// on all 256 CUs -> demand exceeds ceiling -> memory-bound at last.
// R13 lesson: never split channels INSIDE a wave (load geometry) — split on
// the wave-uniform index instead. R15: write amp tracks output contiguity.
// R11: watch WRITE_SIZE for spill. R10: no fences/cross-block sync.

constexpr int B  = 8;
constexpr int C  = 256;
constexpr int H  = 96;
constexpr int W  = 320;
constexpr int NS = 9;              // 2*D+1 shifts
constexpr int QT = W / 4;          // 80 float4 per row
constexpr int RPB = 3;             // rows per block -> 256 blocks
constexpr int CG  = 2;             // channel groups per block
constexpr int TPG = RPB * QT;      // 240 threads per group
constexpr int NTH = CG * TPG;      // 480 threads = 7.5 waves
constexpr int CPG = C / CG;        // 128 channels per group
constexpr int HW  = H * W;
constexpr int PADW = W + 8;        // 4-float zero halo each side
constexpr int NSTEP = CPG / 2;     // 64 STEPs, 2 channels each

__global__ __launch_bounds__(NTH, 1)
void cv_kernel(const float* __restrict__ f1,
               const float* __restrict__ f2,
               float* __restrict__ out) {
    // 4 channel-slots x 2 cgs x 3 rows; slots {0,1}/{2,3} alternate per STEP.
    __shared__ float buf[4][CG][RPB][PADW];   // 31.5 KB

    const int tid = threadIdx.x;
    const int cg  = tid / TPG;         // channel group (wave-uniform)
    const int t   = tid % TPG;
    const int q   = t % QT;            // float4 index within the row
    const int r   = t / QT;            // h-row within block (0..2)

    const int blk = blockIdx.x;        // 256 blocks = 8b x 32 row-groups
    const int hb  = blk % (H / RPB);
    const int b   = blk / (H / RPB);
    const int h   = hb * RPB + r;

    // This group's channel-0 addresses; group channel c at +c*HW.
    const float* p1 =
        f1 + (((size_t)b * C + (size_t)cg * CPG) * H + (size_t)h) * W + 4 * q;
    const float* p2 =
        f2 + (((size_t)b * C + (size_t)cg * CPG) * H + (size_t)h) * W + 4 * q;

    // Zero halo pads of all 4 slots once (covered by first STEP's barrier).
    if (q == 0) {
#pragma unroll
        for (int p = 0; p < 4; ++p)
#pragma unroll
            for (int k = 0; k < 4; ++k) buf[p][cg][r][k] = 0.f;
    }
    if (q == QT - 1) {
#pragma unroll
        for (int p = 0; p < 4; ++p)
#pragma unroll
            for (int k = 0; k < 4; ++k) buf[p][cg][r][4 + W + k] = 0.f;
    }

    float acc[4][NS];
#pragma unroll
    for (int j = 0; j < 4; ++j)
#pragma unroll
        for (int s = 0; s < NS; ++s) acc[j][s] = 0.0f;

    // Prologue: group channels 0..5 in registers (three pairs in flight).
    float4 a0 = *reinterpret_cast<const float4*>(p1);
    float4 r0 = *reinterpret_cast<const float4*>(p2);
    float4 a1 = *reinterpret_cast<const float4*>(p1 + (size_t)HW);
    float4 r1 = *reinterpret_cast<const float4*>(p2 + (size_t)HW);
    float4 a2 = *reinterpret_cast<const float4*>(p1 + 2 * (size_t)HW);
    float4 r2 = *reinterpret_cast<const float4*>(p2 + 2 * (size_t)HW);
    float4 a3 = *reinterpret_cast<const float4*>(p1 + 3 * (size_t)HW);
    float4 r3 = *reinterpret_cast<const float4*>(p2 + 3 * (size_t)HW);
    float4 a4 = *reinterpret_cast<const float4*>(p1 + 4 * (size_t)HW);
    float4 r4 = *reinterpret_cast<const float4*>(p2 + 4 * (size_t)HW);
    float4 a5 = *reinterpret_cast<const float4*>(p1 + 5 * (size_t)HW);
    float4 r5 = *reinterpret_cast<const float4*>(p2 + 5 * (size_t)HW);
    int cL = 6;   // next group-channel to issue; clamped (dummy hot reload)

    // STEP: consume channels (a0,r0),(a1,r1) via LDS slots P0,P1; issue the
    // pair cL,cL+1 (lands 3 STEPs from now). ds_write's implicit vmcnt wait
    // targets loads issued 3 STEPs ago -> long since landed.
#define CV_FMA(AV, X0, RM, X2)                                             \
    {                                                                      \
        const float xw[12] = {X0.x, X0.y, X0.z, X0.w,                      \
                              RM.x, RM.y, RM.z, RM.w,                      \
                              X2.x, X2.y, X2.z, X2.w};                     \
        const float av[4] = {AV.x, AV.y, AV.z, AV.w};                      \
        _Pragma("unroll")                                                  \
        for (int j = 0; j < 4; ++j)                                        \
            _Pragma("unroll")                                              \
            for (int s = 0; s < NS; ++s)                                   \
                acc[j][s] = fmaf(av[j], xw[j + s], acc[j][s]);             \
    }

#define STEP(P0, P1)                                                       \
    {                                                                      \
        *reinterpret_cast<float4*>(&buf[P0][cg][r][4 + 4 * q]) = r0;       \
        *reinterpret_cast<float4*>(&buf[P1][cg][r][4 + 4 * q]) = r1;       \
        const float4 aL0 = *reinterpret_cast<const float4*>(               \
            p1 + (size_t)cL * HW);                                         \
        const float4 rL0 = *reinterpret_cast<const float4*>(               \
            p2 + (size_t)cL * HW);                                         \
        const float4 aL1 = *reinterpret_cast<const float4*>(               \
            p1 + (size_t)(cL + 1) * HW);                                   \
        const float4 rL1 = *reinterpret_cast<const float4*>(               \
            p2 + (size_t)(cL + 1) * HW);                                   \
        cL = (cL < CPG - 2) ? cL + 2 : cL;                                 \
        asm volatile("s_waitcnt lgkmcnt(0)" ::: "memory");                 \
        __builtin_amdgcn_s_barrier();                                      \
        asm volatile("" ::: "memory");                                     \
        const float4 x0a =                                                 \
            *reinterpret_cast<const float4*>(&buf[P0][cg][r][4 * q]);      \
        const float4 x2a =                                                 \
            *reinterpret_cast<const float4*>(&buf[P0][cg][r][4 * q + 8]);  \
        const float4 x0b =                                                 \
            *reinterpret_cast<const float4*>(&buf[P1][cg][r][4 * q]);      \
        const float4 x2b =                                                 \
            *reinterpret_cast<const float4*>(&buf[P1][cg][r][4 * q + 8]);  \
        CV_FMA(a0, x0a, r0, x2a)                                           \
        CV_FMA(a1, x0b, r1, x2b)                                           \
        a0 = a2; r0 = r2; a1 = a3; r1 = r3;                                \
        a2 = a4; r2 = r4; a3 = a5; r3 = r5;                                \
        a4 = aL0; r4 = rL0; a5 = aL1; r5 = rL1;                            \
    }

#pragma unroll 1
    for (int s = 0; s < NSTEP; s += 2) {
        STEP(0, 1)
        STEP(2, 3)
    }
#undef STEP
#undef CV_FMA

    // Epilogue: cross-cg sum via LDS stage, then exact-write float4 stores.
    // Per plane: cg1 stages its 4 sums; cg0 adds and stores. Per plane per
    // block: 3 h-rows x 1280B = 3840B contiguous (R17-proven pattern).
    const float scale = 1.0f / (float)C;
    float* stage = &buf[0][0][0][0];   // reuse: 240 float4 = 3.84 KB
    float* obase = out + (((size_t)b * NS) * H + h) * (size_t)W + 4 * q;
#pragma unroll 1
    for (int s = 0; s < NS; ++s) {
        __syncthreads();
        if (cg == 1) {
            *reinterpret_cast<float4*>(&stage[4 * t]) =
                make_float4(acc[0][s], acc[1][s], acc[2][s], acc[3][s]);
        }
        __syncthreads();
        if (cg == 0) {
            const float4 o = *reinterpret_cast<const float4*>(&stage[4 * t]);
            float4 v = make_float4((acc[0][s] + o.x) * scale,
                                   (acc[1][s] + o.y) * scale,
                                   (acc[2][s] + o.z) * scale,
                                   (acc[3][s] + o.w) * scale);
            *reinterpret_cast<float4*>(obase + (size_t)s * HW) = v;
        }
    }
}

extern "C" void kernel_launch(void* const* d_in, const int* in_sizes, int n_in,
                              void* d_out, int out_size, void* d_ws, size_t ws_size,
                              hipStream_t stream) {
    const float* f1 = (const float*)d_in[0];
    const float* f2 = (const float*)d_in[1];
    float* out = (float*)d_out;

    dim3 grid(B * (H / RPB));   // 256 blocks = 1 per CU
    dim3 block(NTH);            // 480 threads = 7.5 waves
    hipLaunchKernelGGL(cv_kernel, grid, block, 0, stream, f1, f2, out);
}

// Round 20
// 103.292 us; speedup vs baseline: 1.1014x; 1.1014x over previous
//
#include <hip/hip_runtime.h>

// Cost volume, D=4: out[b,s,h,w] = mean_c feat1[b,c,h,w] * feat2[b,c,h,w+s-4]
// feat1/feat2: (8, 256, 96, 320) f32; out: (8, 9, 96, 320) f32.
// R20 = R16 per-wave structure (RPB=4, 5KB chunks, depth-3-pair prefetch,
// 2 channels/STEP, padded-LDS windows, lgkmcnt(0)+raw-barrier) x 2 channel
// groups on the WAVE-ALIGNED slow index (cg = tid/320, TPG = 5 waves exact),
// 640 threads, grid 192. Epilogue = single straight-line store burst:
// stage cg1's 9 planes in LDS (1 barrier), cg0 adds + stores 9 float4.
// R18 lessons: (a) write amplification is caused by BARRIER-SEPARATED store
// bursts (R13/14/18 amplified; R2/5/15/16/17 single-burst = exact), not by
// footprint; (b) group boundaries must be wave-aligned or loads split.
// R13: never split channels inside a wave. R11: watch WRITE for spill.
// R10: no fences/cross-block sync.

constexpr int B  = 8;
constexpr int C  = 256;
constexpr int H  = 96;
constexpr int W  = 320;
constexpr int NS = 9;              // 2*D+1 shifts
constexpr int QT = W / 4;          // 80 float4 per row
constexpr int RPB = 4;             // rows per block -> 192 blocks
constexpr int CG  = 2;             // channel groups per block
constexpr int TPG = RPB * QT;      // 320 threads per group = 5 waves EXACT
constexpr int NTH = CG * TPG;      // 640 threads = 10 waves
constexpr int CPG = C / CG;        // 128 channels per group
constexpr int HW  = H * W;
constexpr int PADW = W + 8;        // 4-float zero halo each side
constexpr int NSTEP = CPG / 2;     // 64 STEPs, 2 channels each

__global__ __launch_bounds__(NTH, 1)
void cv_kernel(const float* __restrict__ f1,
               const float* __restrict__ f2,
               float* __restrict__ out) {
    // Main-loop buffers: 4 channel-slots x 2 cgs x 4 rows (42 KB).
    __shared__ float buf[4][CG][RPB][PADW];
    // Epilogue stage: cg1's 9 planes (46 KB). Total 88 KB -> 1 block/CU.
    __shared__ float stage[NS][RPB][W];

    const int tid = threadIdx.x;
    const int cg  = tid / TPG;         // channel group (wave-uniform, aligned)
    const int t   = tid % TPG;
    const int q   = t % QT;            // float4 index within the row
    const int r   = t / QT;            // h-row within block (0..3)

    const int blk = blockIdx.x;        // 192 blocks = 8b x 24 row-groups
    const int hb  = blk % (H / RPB);
    const int b   = blk / (H / RPB);
    const int h   = hb * RPB + r;

    // This group's channel-0 addresses; group channel c at +c*HW.
    const float* p1 =
        f1 + (((size_t)b * C + (size_t)cg * CPG) * H + (size_t)h) * W + 4 * q;
    const float* p2 =
        f2 + (((size_t)b * C + (size_t)cg * CPG) * H + (size_t)h) * W + 4 * q;

    // Zero halo pads of all 4 slots once (covered by first STEP's barrier).
    if (q == 0) {
#pragma unroll
        for (int p = 0; p < 4; ++p)
#pragma unroll
            for (int k = 0; k < 4; ++k) buf[p][cg][r][k] = 0.f;
    }
    if (q == QT - 1) {
#pragma unroll
        for (int p = 0; p < 4; ++p)
#pragma unroll
            for (int k = 0; k < 4; ++k) buf[p][cg][r][4 + W + k] = 0.f;
    }

    float acc[4][NS];
#pragma unroll
    for (int j = 0; j < 4; ++j)
#pragma unroll
        for (int s = 0; s < NS; ++s) acc[j][s] = 0.0f;

    // Prologue: group channels 0..5 in registers (three pairs in flight).
    float4 a0 = *reinterpret_cast<const float4*>(p1);
    float4 r0 = *reinterpret_cast<const float4*>(p2);
    float4 a1 = *reinterpret_cast<const float4*>(p1 + (size_t)HW);
    float4 r1 = *reinterpret_cast<const float4*>(p2 + (size_t)HW);
    float4 a2 = *reinterpret_cast<const float4*>(p1 + 2 * (size_t)HW);
    float4 r2 = *reinterpret_cast<const float4*>(p2 + 2 * (size_t)HW);
    float4 a3 = *reinterpret_cast<const float4*>(p1 + 3 * (size_t)HW);
    float4 r3 = *reinterpret_cast<const float4*>(p2 + 3 * (size_t)HW);
    float4 a4 = *reinterpret_cast<const float4*>(p1 + 4 * (size_t)HW);
    float4 r4 = *reinterpret_cast<const float4*>(p2 + 4 * (size_t)HW);
    float4 a5 = *reinterpret_cast<const float4*>(p1 + 5 * (size_t)HW);
    float4 r5 = *reinterpret_cast<const float4*>(p2 + 5 * (size_t)HW);
    int cL = 6;   // next group-channel to issue; clamped (dummy hot reload)

    // STEP: consume channels (a0,r0),(a1,r1) via LDS slots P0,P1; issue the
    // pair cL,cL+1 (lands 3 STEPs from now). ds_write's implicit vmcnt wait
    // targets loads issued 3 STEPs ago -> long since landed.
#define CV_FMA(AV, X0, RM, X2)                                             \
    {                                                                      \
        const float xw[12] = {X0.x, X0.y, X0.z, X0.w,                      \
                              RM.x, RM.y, RM.z, RM.w,                      \
                              X2.x, X2.y, X2.z, X2.w};                     \
        const float av[4] = {AV.x, AV.y, AV.z, AV.w};                      \
        _Pragma("unroll")                                                  \
        for (int j = 0; j < 4; ++j)                                        \
            _Pragma("unroll")                                              \
            for (int s = 0; s < NS; ++s)                                   \
                acc[j][s] = fmaf(av[j], xw[j + s], acc[j][s]);             \
    }

#define STEP(P0, P1)                                                       \
    {                                                                      \
        *reinterpret_cast<float4*>(&buf[P0][cg][r][4 + 4 * q]) = r0;       \
        *reinterpret_cast<float4*>(&buf[P1][cg][r][4 + 4 * q]) = r1;       \
        const float4 aL0 = *reinterpret_cast<const float4*>(               \
            p1 + (size_t)cL * HW);                                         \
        const float4 rL0 = *reinterpret_cast<const float4*>(               \
            p2 + (size_t)cL * HW);                                         \
        const float4 aL1 = *reinterpret_cast<const float4*>(               \
            p1 + (size_t)(cL + 1) * HW);                                   \
        const float4 rL1 = *reinterpret_cast<const float4*>(               \
            p2 + (size_t)(cL + 1) * HW);                                   \
        cL = (cL < CPG - 2) ? cL + 2 : cL;                                 \
        asm volatile("s_waitcnt lgkmcnt(0)" ::: "memory");                 \
        __builtin_amdgcn_s_barrier();                                      \
        asm volatile("" ::: "memory");                                     \
        const float4 x0a =                                                 \
            *reinterpret_cast<const float4*>(&buf[P0][cg][r][4 * q]);      \
        const float4 x2a =                                                 \
            *reinterpret_cast<const float4*>(&buf[P0][cg][r][4 * q + 8]);  \
        const float4 x0b =                                                 \
            *reinterpret_cast<const float4*>(&buf[P1][cg][r][4 * q]);      \
        const float4 x2b =                                                 \
            *reinterpret_cast<const float4*>(&buf[P1][cg][r][4 * q + 8]);  \
        CV_FMA(a0, x0a, r0, x2a)                                           \
        CV_FMA(a1, x0b, r1, x2b)                                           \
        a0 = a2; r0 = r2; a1 = a3; r1 = r3;                                \
        a2 = a4; r2 = r4; a3 = a5; r3 = r5;                                \
        a4 = aL0; r4 = rL0; a5 = aL1; r5 = rL1;                            \
    }

#pragma unroll 1
    for (int s = 0; s < NSTEP; s += 2) {
        STEP(0, 1)
        STEP(2, 3)
    }
#undef STEP
#undef CV_FMA

    // Epilogue: cg1 stages ALL 9 planes (straight-line ds_writes), one
    // barrier, then cg0 adds and emits ALL 9 float4 global stores in ONE
    // straight-line burst (exact-write pattern, R17-proven).
    const float scale = 1.0f / (float)C;
    __syncthreads();
    if (cg == 1) {
#pragma unroll
        for (int s = 0; s < NS; ++s) {
            *reinterpret_cast<float4*>(&stage[s][r][4 * q]) =
                make_float4(acc[0][s], acc[1][s], acc[2][s], acc[3][s]);
        }
    }
    __syncthreads();
    if (cg == 0) {
        float* obase = out + (((size_t)b * NS) * H + h) * (size_t)W + 4 * q;
#pragma unroll
        for (int s = 0; s < NS; ++s) {
            const float4 o = *reinterpret_cast<const float4*>(&stage[s][r][4 * q]);
            float4 v = make_float4((acc[0][s] + o.x) * scale,
                                   (acc[1][s] + o.y) * scale,
                                   (acc[2][s] + o.z) * scale,
                                   (acc[3][s] + o.w) * scale);
            *reinterpret_cast<float4*>(obase + (size_t)s * HW) = v;
        }
    }
}

extern "C" void kernel_launch(void* const* d_in, const int* in_sizes, int n_in,
                              void* d_out, int out_size, void* d_ws, size_t ws_size,
                              hipStream_t stream) {
    const float* f1 = (const float*)d_in[0];
    const float* f2 = (const float*)d_in[1];
    float* out = (float*)d_out;

    dim3 grid(B * (H / RPB));   // 192 blocks
    dim3 block(NTH);            // 640 threads = 10 waves
    hipLaunchKernelGGL(cv_kernel, grid, block, 0, stream, f1, f2, out);
}

// Round 21
// 92.576 us; speedup vs baseline: 1.2289x; 1.1158x over previous
//
#include <hip/hip_runtime.h>

// Cost volume, D=4: out[b,s,h,w] = mean_c feat1[b,c,h,w] * feat2[b,c,h,w+s-4]
// feat1/feat2: (8, 256, 96, 320) f32; out: (8, 9, 96, 320) f32.
// R21: 256 blocks (ALL CUs) x 8 waves. RPB=3, CG=2 channel groups PADDED to
// 256 threads (4 waves) each -> wave-aligned groups on a 256-block grid.
// Inactive lanes (t>=240, 16/group) do clamped dummy loads + dump ds_writes
// so STEP stays branch-free (all waves reach the barrier).
// Model from R16/17/20: per-CU delivered BW saturates ~26-27 GB/s beyond ~5
// waves; chip ceiling 6.3 TB/s needs all 256 CUs AND >=5 waves each.
// R20: single-burst epilogue = near-exact writes. R18: wave-aligned groups.
// R13: never split channels inside a wave. R11: watch WRITE for spill.
// R10: no fences/cross-block sync.

constexpr int B  = 8;
constexpr int C  = 256;
constexpr int H  = 96;
constexpr int W  = 320;
constexpr int NS = 9;              // 2*D+1 shifts
constexpr int QT = W / 4;          // 80 float4 per row
constexpr int RPB = 3;             // rows per block -> 256 blocks
constexpr int CG  = 2;             // channel groups per block
constexpr int TPG = 256;           // threads per group (PADDED, 4 waves exact)
constexpr int ACT = RPB * QT;      // 240 active threads per group
constexpr int NTH = CG * TPG;      // 512 threads = 8 waves
constexpr int CPG = C / CG;        // 128 channels per group
constexpr int HW  = H * W;
constexpr int PADW = W + 8;        // 4-float zero halo each side
constexpr int NSTEP = CPG / 2;     // 64 STEPs, 2 channels each

__global__ __launch_bounds__(NTH, 1)
void cv_kernel(const float* __restrict__ f1,
               const float* __restrict__ f2,
               float* __restrict__ out) {
    // Main-loop buffers: 4 channel-slots x 2 cgs x 3 rows (31.5 KB).
    __shared__ float buf[4][CG][RPB][PADW];
    // Epilogue stage: cg1's 9 planes (34.6 KB).
    __shared__ float stage[NS][RPB][W];
    // Dump for inactive lanes' ds_writes (own slot each -> no conflicts).
    __shared__ float dump[CG * 16 * 4];

    const int tid = threadIdx.x;
    const int cg  = tid / TPG;         // channel group (wave-aligned)
    const int t   = tid % TPG;
    const bool active = (t < ACT);
    const int te  = active ? t : ACT - 1;   // clamped for addresses
    const int q   = te % QT;           // float4 index within the row
    const int r   = te / QT;           // h-row within block (0..2)

    const int blk = blockIdx.x;        // 256 blocks = 8b x 32 row-groups
    const int hb  = blk % (H / RPB);
    const int b   = blk / (H / RPB);
    const int h   = hb * RPB + r;

    // This group's channel-0 addresses; group channel c at +c*HW.
    const float* p1 =
        f1 + (((size_t)b * C + (size_t)cg * CPG) * H + (size_t)h) * W + 4 * q;
    const float* p2 =
        f2 + (((size_t)b * C + (size_t)cg * CPG) * H + (size_t)h) * W + 4 * q;

    // LDS write pointers per slot: active -> padded window; inactive -> dump.
    float* w0 = active ? &buf[0][cg][r][4 + 4 * q] : &dump[4 * (cg * 16 + (t - ACT))];
    float* w1 = active ? &buf[1][cg][r][4 + 4 * q] : &dump[4 * (cg * 16 + (t - ACT))];
    float* w2 = active ? &buf[2][cg][r][4 + 4 * q] : &dump[4 * (cg * 16 + (t - ACT))];
    float* w3 = active ? &buf[3][cg][r][4 + 4 * q] : &dump[4 * (cg * 16 + (t - ACT))];

    // Zero halo pads of all 4 slots once (covered by first STEP's barrier).
    if (active && q == 0) {
#pragma unroll
        for (int p = 0; p < 4; ++p)
#pragma unroll
            for (int k = 0; k < 4; ++k) buf[p][cg][r][k] = 0.f;
    }
    if (active && q == QT - 1) {
#pragma unroll
        for (int p = 0; p < 4; ++p)
#pragma unroll
            for (int k = 0; k < 4; ++k) buf[p][cg][r][4 + W + k] = 0.f;
    }

    float acc[4][NS];
#pragma unroll
    for (int j = 0; j < 4; ++j)
#pragma unroll
        for (int s = 0; s < NS; ++s) acc[j][s] = 0.0f;

    // Prologue: group channels 0..5 in registers (three pairs in flight).
    float4 a0 = *reinterpret_cast<const float4*>(p1);
    float4 r0 = *reinterpret_cast<const float4*>(p2);
    float4 a1 = *reinterpret_cast<const float4*>(p1 + (size_t)HW);
    float4 r1 = *reinterpret_cast<const float4*>(p2 + (size_t)HW);
    float4 a2 = *reinterpret_cast<const float4*>(p1 + 2 * (size_t)HW);
    float4 r2 = *reinterpret_cast<const float4*>(p2 + 2 * (size_t)HW);
    float4 a3 = *reinterpret_cast<const float4*>(p1 + 3 * (size_t)HW);
    float4 r3 = *reinterpret_cast<const float4*>(p2 + 3 * (size_t)HW);
    float4 a4 = *reinterpret_cast<const float4*>(p1 + 4 * (size_t)HW);
    float4 r4 = *reinterpret_cast<const float4*>(p2 + 4 * (size_t)HW);
    float4 a5 = *reinterpret_cast<const float4*>(p1 + 5 * (size_t)HW);
    float4 r5 = *reinterpret_cast<const float4*>(p2 + 5 * (size_t)HW);
    int cL = 6;   // next group-channel to issue; clamped (dummy hot reload)

    // STEP: consume channels (a0,r0),(a1,r1) via LDS slots P0,P1; issue the
    // pair cL,cL+1 (lands 3 STEPs from now). ds_write's implicit vmcnt wait
    // targets loads issued 3 STEPs ago -> long since landed. Branch-free:
    // inactive lanes write to dump / read clamped addresses.
#define CV_FMA(AV, X0, RM, X2)                                             \
    {                                                                      \
        const float xw[12] = {X0.x, X0.y, X0.z, X0.w,                      \
                              RM.x, RM.y, RM.z, RM.w,                      \
                              X2.x, X2.y, X2.z, X2.w};                     \
        const float av[4] = {AV.x, AV.y, AV.z, AV.w};                      \
        _Pragma("unroll")                                                  \
        for (int j = 0; j < 4; ++j)                                        \
            _Pragma("unroll")                                              \
            for (int s = 0; s < NS; ++s)                                   \
                acc[j][s] = fmaf(av[j], xw[j + s], acc[j][s]);             \
    }

#define STEP(P0, P1)                                                       \
    {                                                                      \
        *reinterpret_cast<float4*>(w##P0) = r0;                            \
        *reinterpret_cast<float4*>(w##P1) = r1;                            \
        const float4 aL0 = *reinterpret_cast<const float4*>(               \
            p1 + (size_t)cL * HW);                                         \
        const float4 rL0 = *reinterpret_cast<const float4*>(               \
            p2 + (size_t)cL * HW);                                         \
        const float4 aL1 = *reinterpret_cast<const float4*>(               \
            p1 + (size_t)(cL + 1) * HW);                                   \
        const float4 rL1 = *reinterpret_cast<const float4*>(               \
            p2 + (size_t)(cL + 1) * HW);                                   \
        cL = (cL < CPG - 2) ? cL + 2 : cL;                                 \
        asm volatile("s_waitcnt lgkmcnt(0)" ::: "memory");                 \
        __builtin_amdgcn_s_barrier();                                      \
        asm volatile("" ::: "memory");                                     \
        const float4 x0a =                                                 \
            *reinterpret_cast<const float4*>(&buf[P0][cg][r][4 * q]);      \
        const float4 x2a =                                                 \
            *reinterpret_cast<const float4*>(&buf[P0][cg][r][4 * q + 8]);  \
        const float4 x0b =                                                 \
            *reinterpret_cast<const float4*>(&buf[P1][cg][r][4 * q]);      \
        const float4 x2b =                                                 \
            *reinterpret_cast<const float4*>(&buf[P1][cg][r][4 * q + 8]);  \
        CV_FMA(a0, x0a, r0, x2a)                                           \
        CV_FMA(a1, x0b, r1, x2b)                                           \
        a0 = a2; r0 = r2; a1 = a3; r1 = r3;                                \
        a2 = a4; r2 = r4; a3 = a5; r3 = r5;                                \
        a4 = aL0; r4 = rL0; a5 = aL1; r5 = rL1;                            \
    }

#pragma unroll 1
    for (int s = 0; s < NSTEP; s += 2) {
        STEP(0, 1)
        STEP(2, 3)
    }
#undef STEP
#undef CV_FMA

    // Epilogue: cg1 stages ALL 9 planes straight-line, one barrier, cg0
    // adds and emits ALL 9 float4 stores in ONE burst (R20-proven pattern).
    const float scale = 1.0f / (float)C;
    __syncthreads();
    if (cg == 1 && active) {
#pragma unroll
        for (int s = 0; s < NS; ++s) {
            *reinterpret_cast<float4*>(&stage[s][r][4 * q]) =
                make_float4(acc[0][s], acc[1][s], acc[2][s], acc[3][s]);
        }
    }
    __syncthreads();
    if (cg == 0 && active) {
        float* obase = out + (((size_t)b * NS) * H + h) * (size_t)W + 4 * q;
#pragma unroll
        for (int s = 0; s < NS; ++s) {
            const float4 o = *reinterpret_cast<const float4*>(&stage[s][r][4 * q]);
            float4 v = make_float4((acc[0][s] + o.x) * scale,
                                   (acc[1][s] + o.y) * scale,
                                   (acc[2][s] + o.z) * scale,
                                   (acc[3][s] + o.w) * scale);
            *reinterpret_cast<float4*>(obase + (size_t)s * HW) = v;
        }
    }
}

extern "C" void kernel_launch(void* const* d_in, const int* in_sizes, int n_in,
                              void* d_out, int out_size, void* d_ws, size_t ws_size,
                              hipStream_t stream) {
    const float* f1 = (const float*)d_in[0];
    const float* f2 = (const float*)d_in[1];
    float* out = (float*)d_out;

    dim3 grid(B * (H / RPB));   // 256 blocks = 1 per CU
    dim3 block(NTH);            // 512 threads = 8 waves
    hipLaunchKernelGGL(cv_kernel, grid, block, 0, stream, f1, f2, out);
}